// Round 1
// baseline (5819.599 us; speedup 1.0000x reference)
//
#include <hip/hip_runtime.h>

#define NN 100000
#define NE 1600000
#define DD 128

// ---------------- degree ----------------
__global__ __launch_bounds__(256) void deg_kernel(const int* __restrict__ dst,
                                                  float* __restrict__ deg) {
    int e = blockIdx.x * 256 + threadIdx.x;
    if (e < NE) atomicAdd(&deg[dst[e]], 1.0f);
}

__global__ __launch_bounds__(256) void invdeg_kernel(float* __restrict__ deg) {
    int i = blockIdx.x * 256 + threadIdx.x;
    if (i < NN) deg[i] = 1.0f / fmaxf(deg[i], 1.0f);
}

// ---------------- scatter-add: agg[dst] += feat[src] ----------------
// one thread per (edge, 4 features): 32 threads/edge, float4 gather + 4 atomics
__global__ __launch_bounds__(256) void scatter_kernel(const float* __restrict__ feat,
                                                      const int* __restrict__ src,
                                                      const int* __restrict__ dst,
                                                      float* __restrict__ agg) {
    int tid = blockIdx.x * 256 + threadIdx.x;   // < NE*32 (exact grid)
    int e = tid >> 5;
    int q = (tid & 31) * 4;
    int s = src[e];
    int d = dst[e];
    const float4 v = *(const float4*)&feat[(size_t)s * DD + q];
    float* b = &agg[(size_t)d * DD + q];
    atomicAdd(b + 0, v.x);
    atomicAdd(b + 1, v.y);
    atomicAdd(b + 2, v.z);
    atomicAdd(b + 3, v.w);
}

// ---------------- combine: out = invdeg*(agg@Wl^T) + x@Wr^T + b [, relu] ----
// grid.y = column half (64 cols). LDS: both weight halves transposed,
// stride 64 floats -> reads/writes are <=2-way bank aliased (free on gfx950).
// Thread tile: 4 nodes x 4 cols, k in quads via float4.
__global__ __launch_bounds__(256) void combine_kernel(
    const float* __restrict__ xin, const float* __restrict__ agg,
    const float* __restrict__ invdeg,
    const float* __restrict__ Wl, const float* __restrict__ Wr,
    const float* __restrict__ bias, float* __restrict__ out, int do_relu)
{
    __shared__ float Wlt[DD * 64];   // Wlt[k*64 + j] = Wl[(jh*64+j)*128 + k]
    __shared__ float Wrt[DD * 64];
    const int t  = threadIdx.x;
    const int jh = blockIdx.y;

    // transposed weight load (one-time per block)
    for (int idx = t; idx < 64 * 32; idx += 256) {
        int j  = idx & 63;       // lane-varying -> conflict-light LDS writes
        int kq = idx >> 6;       // 0..31
        float4 wl = *(const float4*)&Wl[(size_t)(jh * 64 + j) * DD + kq * 4];
        float4 wr = *(const float4*)&Wr[(size_t)(jh * 64 + j) * DD + kq * 4];
        Wlt[(kq * 4 + 0) * 64 + j] = wl.x;
        Wlt[(kq * 4 + 1) * 64 + j] = wl.y;
        Wlt[(kq * 4 + 2) * 64 + j] = wl.z;
        Wlt[(kq * 4 + 3) * 64 + j] = wl.w;
        Wrt[(kq * 4 + 0) * 64 + j] = wr.x;
        Wrt[(kq * 4 + 1) * 64 + j] = wr.y;
        Wrt[(kq * 4 + 2) * 64 + j] = wr.z;
        Wrt[(kq * 4 + 3) * 64 + j] = wr.w;
    }
    __syncthreads();

    const int jj4     = (t & 15) * 4;   // 16 col-groups of 4
    const int ng      = t >> 4;         // 16 node-groups of 4 nodes
    const int colbase = jh * 64 + jj4;
    const float4 b4   = *(const float4*)&bias[colbase];

    for (int base = blockIdx.x * 64; base < NN; base += gridDim.x * 64) {
        const int n0 = base + ng * 4;
        if (n0 >= NN) continue;
        // clamp node indices for the (rare) tail; stores are predicated
        size_t row[4];
        #pragma unroll
        for (int i = 0; i < 4; ++i) {
            int n = n0 + i; if (n > NN - 1) n = NN - 1;
            row[i] = (size_t)n * DD;
        }
        float accl[4][4] = {{0}}, accr[4][4] = {{0}};
        for (int kq = 0; kq < DD; kq += 4) {
            float4 xv[4], av[4];
            #pragma unroll
            for (int i = 0; i < 4; ++i) {
                xv[i] = *(const float4*)&xin[row[i] + kq];
                av[i] = *(const float4*)&agg[row[i] + kq];
            }
            #pragma unroll
            for (int kk = 0; kk < 4; ++kk) {
                const float4 wl = *(const float4*)&Wlt[(kq + kk) * 64 + jj4];
                const float4 wr = *(const float4*)&Wrt[(kq + kk) * 64 + jj4];
                #pragma unroll
                for (int i = 0; i < 4; ++i) {
                    const float ak = ((const float*)&av[i])[kk];
                    const float xk = ((const float*)&xv[i])[kk];
                    accl[i][0] += ak * wl.x; accl[i][1] += ak * wl.y;
                    accl[i][2] += ak * wl.z; accl[i][3] += ak * wl.w;
                    accr[i][0] += xk * wr.x; accr[i][1] += xk * wr.y;
                    accr[i][2] += xk * wr.z; accr[i][3] += xk * wr.w;
                }
            }
        }
        #pragma unroll
        for (int i = 0; i < 4; ++i) {
            const int n = n0 + i;
            if (n >= NN) break;
            const float id = invdeg[n];
            float4 o;
            o.x = accl[i][0] * id + accr[i][0] + b4.x;
            o.y = accl[i][1] * id + accr[i][1] + b4.y;
            o.z = accl[i][2] * id + accr[i][2] + b4.z;
            o.w = accl[i][3] * id + accr[i][3] + b4.w;
            if (do_relu) {
                o.x = fmaxf(o.x, 0.0f); o.y = fmaxf(o.y, 0.0f);
                o.z = fmaxf(o.z, 0.0f); o.w = fmaxf(o.w, 0.0f);
            }
            *(float4*)&out[(size_t)n * DD + colbase] = o;
        }
    }
}

extern "C" void kernel_launch(void* const* d_in, const int* in_sizes, int n_in,
                              void* d_out, int out_size, void* d_ws, size_t ws_size,
                              hipStream_t stream) {
    const float* x   = (const float*)d_in[0];
    const int*   ei  = (const int*)d_in[1];
    const float* Wl1 = (const float*)d_in[2];
    const float* Wr1 = (const float*)d_in[3];
    const float* b1  = (const float*)d_in[4];
    const float* Wl2 = (const float*)d_in[5];
    const float* Wr2 = (const float*)d_in[6];
    const float* b2  = (const float*)d_in[7];
    const int* src = ei;
    const int* dst = ei + NE;
    float* out = (float*)d_out;

    // workspace layout: agg [N*D] | invdeg [N] | h [N*D]
    float* agg    = (float*)d_ws;
    float* invdeg = agg + (size_t)NN * DD;
    float* h      = invdeg + NN;

    // zero agg + deg
    hipMemsetAsync(agg, 0, ((size_t)NN * DD + NN) * sizeof(float), stream);

    deg_kernel<<<(NE + 255) / 256, 256, 0, stream>>>(dst, invdeg);
    scatter_kernel<<<NE / 8, 256, 0, stream>>>(x, src, dst, agg);   // NE*32/256
    invdeg_kernel<<<(NN + 255) / 256, 256, 0, stream>>>(invdeg);
    combine_kernel<<<dim3(512, 2), 256, 0, stream>>>(x, agg, invdeg, Wl1, Wr1, b1, h, 1);

    hipMemsetAsync(agg, 0, (size_t)NN * DD * sizeof(float), stream);
    scatter_kernel<<<NE / 8, 256, 0, stream>>>(h, src, dst, agg);
    combine_kernel<<<dim3(512, 2), 256, 0, stream>>>(h, agg, invdeg, Wl2, Wr2, b2, out, 0);
}

// Round 2
// 832.468 us; speedup vs baseline: 6.9908x; 6.9908x over previous
//
#include <hip/hip_runtime.h>

#define NN 100000
#define NE 1600000
#define DD 128

// ---------------- degree count (int) ----------------
__global__ __launch_bounds__(256) void count_kernel(const int* __restrict__ dst,
                                                    int* __restrict__ cnt) {
    int e = blockIdx.x * 256 + threadIdx.x;
    if (e < NE) atomicAdd(&cnt[dst[e]], 1);
}

// ---------------- single-block exclusive scan over NN counts ----------------
__global__ __launch_bounds__(1024) void scan_kernel(const int* __restrict__ cnt,
                                                    int* __restrict__ rowoff) {
    __shared__ int wsum[16];
    const int t = threadIdx.x;
    const int lane = t & 63, wv = t >> 6;
    int carry = 0;
    for (int base = 0; base < NN; base += 1024) {
        int i = base + t;
        int v = (i < NN) ? cnt[i] : 0;
        int s = v;                              // wave inclusive scan
        #pragma unroll
        for (int d = 1; d < 64; d <<= 1) {
            int u = __shfl_up(s, d, 64);
            if (lane >= d) s += u;
        }
        if (lane == 63) wsum[wv] = s;
        __syncthreads();
        if (wv == 0 && lane < 16) {
            int ws = wsum[lane];
            #pragma unroll
            for (int d = 1; d < 16; d <<= 1) {
                int u = __shfl_up(ws, d, 64);
                if (lane >= d) ws += u;
            }
            wsum[lane] = ws;                    // inclusive over wave sums
        }
        __syncthreads();
        int wave_excl = (wv == 0) ? 0 : wsum[wv - 1];
        if (i < NN) rowoff[i] = carry + wave_excl + (s - v);
        int total = wsum[15];
        __syncthreads();                        // protect wsum for next chunk
        carry += total;
    }
    if (t == 0) rowoff[NN] = carry;
}

__global__ __launch_bounds__(256) void invdeg_kernel(const int* __restrict__ cnt,
                                                     float* __restrict__ invdeg) {
    int i = blockIdx.x * 256 + threadIdx.x;
    if (i < NN) invdeg[i] = 1.0f / fmaxf((float)cnt[i], 1.0f);
}

// ---------------- CSR placement ----------------
__global__ __launch_bounds__(256) void place_kernel(const int* __restrict__ src,
                                                    const int* __restrict__ dst,
                                                    int* __restrict__ cursor,
                                                    int* __restrict__ csr) {
    int e = blockIdx.x * 256 + threadIdx.x;
    if (e < NE) {
        int pos = atomicAdd(&cursor[dst[e]], 1);
        csr[pos] = src[e];
    }
}

// ---------------- gather: agg[n] = sum_{s in N(n)} feat[s] ----------------
// 32 lanes per node (float4 over 128 cols), 8 nodes per 256-block.
__global__ __launch_bounds__(256) void gather_kernel(const float* __restrict__ feat,
                                                     const int* __restrict__ rowoff,
                                                     const int* __restrict__ csr,
                                                     float* __restrict__ agg) {
    int node = blockIdx.x * 8 + (threadIdx.x >> 5);
    if (node >= NN) return;
    int q = (threadIdx.x & 31) * 4;
    int beg = rowoff[node], end = rowoff[node + 1];
    float4 acc = {0.f, 0.f, 0.f, 0.f};
    for (int j = beg; j < end; ++j) {
        int s = csr[j];
        const float4 v = *(const float4*)&feat[(size_t)s * DD + q];
        acc.x += v.x; acc.y += v.y; acc.z += v.z; acc.w += v.w;
    }
    *(float4*)&agg[(size_t)node * DD + q] = acc;
}

// ---------------- combine: out = invdeg*(agg@Wl^T) + x@Wr^T + b [, relu] ----
__global__ __launch_bounds__(256) void combine_kernel(
    const float* __restrict__ xin, const float* __restrict__ agg,
    const float* __restrict__ invdeg,
    const float* __restrict__ Wl, const float* __restrict__ Wr,
    const float* __restrict__ bias, float* __restrict__ out, int do_relu)
{
    __shared__ float Wlt[DD * 64];   // Wlt[k*64 + j] = Wl[(jh*64+j)*128 + k]
    __shared__ float Wrt[DD * 64];
    const int t  = threadIdx.x;
    const int jh = blockIdx.y;

    for (int idx = t; idx < 64 * 32; idx += 256) {
        int j  = idx & 63;
        int kq = idx >> 6;
        float4 wl = *(const float4*)&Wl[(size_t)(jh * 64 + j) * DD + kq * 4];
        float4 wr = *(const float4*)&Wr[(size_t)(jh * 64 + j) * DD + kq * 4];
        Wlt[(kq * 4 + 0) * 64 + j] = wl.x;
        Wlt[(kq * 4 + 1) * 64 + j] = wl.y;
        Wlt[(kq * 4 + 2) * 64 + j] = wl.z;
        Wlt[(kq * 4 + 3) * 64 + j] = wl.w;
        Wrt[(kq * 4 + 0) * 64 + j] = wr.x;
        Wrt[(kq * 4 + 1) * 64 + j] = wr.y;
        Wrt[(kq * 4 + 2) * 64 + j] = wr.z;
        Wrt[(kq * 4 + 3) * 64 + j] = wr.w;
    }
    __syncthreads();

    const int jj4     = (t & 15) * 4;
    const int ng      = t >> 4;
    const int colbase = jh * 64 + jj4;
    const float4 b4   = *(const float4*)&bias[colbase];

    for (int base = blockIdx.x * 64; base < NN; base += gridDim.x * 64) {
        const int n0 = base + ng * 4;
        if (n0 >= NN) continue;
        size_t row[4];
        #pragma unroll
        for (int i = 0; i < 4; ++i) {
            int n = n0 + i; if (n > NN - 1) n = NN - 1;
            row[i] = (size_t)n * DD;
        }
        float accl[4][4] = {{0}}, accr[4][4] = {{0}};
        for (int kq = 0; kq < DD; kq += 4) {
            float4 xv[4], av[4];
            #pragma unroll
            for (int i = 0; i < 4; ++i) {
                xv[i] = *(const float4*)&xin[row[i] + kq];
                av[i] = *(const float4*)&agg[row[i] + kq];
            }
            #pragma unroll
            for (int kk = 0; kk < 4; ++kk) {
                const float4 wl = *(const float4*)&Wlt[(kq + kk) * 64 + jj4];
                const float4 wr = *(const float4*)&Wrt[(kq + kk) * 64 + jj4];
                #pragma unroll
                for (int i = 0; i < 4; ++i) {
                    const float ak = ((const float*)&av[i])[kk];
                    const float xk = ((const float*)&xv[i])[kk];
                    accl[i][0] += ak * wl.x; accl[i][1] += ak * wl.y;
                    accl[i][2] += ak * wl.z; accl[i][3] += ak * wl.w;
                    accr[i][0] += xk * wr.x; accr[i][1] += xk * wr.y;
                    accr[i][2] += xk * wr.z; accr[i][3] += xk * wr.w;
                }
            }
        }
        #pragma unroll
        for (int i = 0; i < 4; ++i) {
            const int n = n0 + i;
            if (n >= NN) break;
            const float id = invdeg[n];
            float4 o;
            o.x = accl[i][0] * id + accr[i][0] + b4.x;
            o.y = accl[i][1] * id + accr[i][1] + b4.y;
            o.z = accl[i][2] * id + accr[i][2] + b4.z;
            o.w = accl[i][3] * id + accr[i][3] + b4.w;
            if (do_relu) {
                o.x = fmaxf(o.x, 0.0f); o.y = fmaxf(o.y, 0.0f);
                o.z = fmaxf(o.z, 0.0f); o.w = fmaxf(o.w, 0.0f);
            }
            *(float4*)&out[(size_t)n * DD + colbase] = o;
        }
    }
}

extern "C" void kernel_launch(void* const* d_in, const int* in_sizes, int n_in,
                              void* d_out, int out_size, void* d_ws, size_t ws_size,
                              hipStream_t stream) {
    const float* x   = (const float*)d_in[0];
    const int*   ei  = (const int*)d_in[1];
    const float* Wl1 = (const float*)d_in[2];
    const float* Wr1 = (const float*)d_in[3];
    const float* b1  = (const float*)d_in[4];
    const float* Wl2 = (const float*)d_in[5];
    const float* Wr2 = (const float*)d_in[6];
    const float* b2  = (const float*)d_in[7];
    const int* src = ei;
    const int* dst = ei + NE;
    float* out = (float*)d_out;

    // workspace layout
    float* agg    = (float*)d_ws;                     // NN*DD
    float* h      = agg + (size_t)NN * DD;            // NN*DD
    float* invdeg = h + (size_t)NN * DD;              // NN
    int*   cnt    = (int*)(invdeg + NN);              // NN
    int*   rowoff = cnt + NN;                         // NN+1
    int*   cursor = rowoff + NN + 1;                  // NN
    int*   csr    = cursor + NN;                      // NE

    hipMemsetAsync(cnt, 0, NN * sizeof(int), stream);
    count_kernel<<<(NE + 255) / 256, 256, 0, stream>>>(dst, cnt);
    scan_kernel<<<1, 1024, 0, stream>>>(cnt, rowoff);
    invdeg_kernel<<<(NN + 255) / 256, 256, 0, stream>>>(cnt, invdeg);
    hipMemcpyAsync(cursor, rowoff, NN * sizeof(int), hipMemcpyDeviceToDevice, stream);
    place_kernel<<<(NE + 255) / 256, 256, 0, stream>>>(src, dst, cursor, csr);

    gather_kernel<<<(NN + 7) / 8, 256, 0, stream>>>(x, rowoff, csr, agg);
    combine_kernel<<<dim3(512, 2), 256, 0, stream>>>(x, agg, invdeg, Wl1, Wr1, b1, h, 1);

    gather_kernel<<<(NN + 7) / 8, 256, 0, stream>>>(h, rowoff, csr, agg);
    combine_kernel<<<dim3(512, 2), 256, 0, stream>>>(h, agg, invdeg, Wl2, Wr2, b2, out, 0);
}

// Round 3
// 503.637 us; speedup vs baseline: 11.5552x; 1.6529x over previous
//
#include <hip/hip_runtime.h>
#include <hip/hip_bf16.h>

#define NN 100000
#define NE 1600000
#define DD 128
#define NB 98            // ceil(NN/1024) scan blocks

typedef __attribute__((ext_vector_type(8))) short bf16x8;
typedef __attribute__((ext_vector_type(4))) float f32x4;

__device__ inline unsigned short f2bf(float f) {          // RNE float->bf16
    unsigned u = __builtin_bit_cast(unsigned, f);
    u += 0x7fff + ((u >> 16) & 1);
    return (unsigned short)(u >> 16);
}
__device__ inline float bf2f(unsigned short h) {
    return __builtin_bit_cast(float, (unsigned)h << 16);
}

// ---------------- degree count ----------------
__global__ __launch_bounds__(256) void count_kernel(const int* __restrict__ dst,
                                                    int* __restrict__ cnt) {
    int e = blockIdx.x * 256 + threadIdx.x;
    if (e < NE) atomicAdd(&cnt[e < NE ? dst[e] : 0], 1);
}

// ---------------- 3-phase scan ----------------
__global__ __launch_bounds__(1024) void scan1(const int* __restrict__ cnt,
                                              int* __restrict__ loc,
                                              int* __restrict__ bsum) {
    __shared__ int wsum[16];
    const int t = threadIdx.x, lane = t & 63, wv = t >> 6;
    int i = blockIdx.x * 1024 + t;
    int v = (i < NN) ? cnt[i] : 0;
    int s = v;
    #pragma unroll
    for (int d = 1; d < 64; d <<= 1) {
        int u = __shfl_up(s, d, 64);
        if (lane >= d) s += u;
    }
    if (lane == 63) wsum[wv] = s;
    __syncthreads();
    if (wv == 0 && lane < 16) {
        int ws = wsum[lane];
        #pragma unroll
        for (int d = 1; d < 16; d <<= 1) {
            int u = __shfl_up(ws, d, 64);
            if (lane >= d) ws += u;
        }
        wsum[lane] = ws;
    }
    __syncthreads();
    int excl = ((wv ? wsum[wv - 1] : 0)) + (s - v);
    if (i < NN) loc[i] = excl;
    if (t == 0) bsum[blockIdx.x] = wsum[15];
}

__global__ __launch_bounds__(128) void scan2(const int* __restrict__ bsum,
                                             int* __restrict__ boff) {
    __shared__ int a[128];
    int t = threadIdx.x;
    int v = (t < NB) ? bsum[t] : 0;
    a[t] = v;
    __syncthreads();
    #pragma unroll
    for (int d = 1; d < 128; d <<= 1) {
        int u = (t >= d) ? a[t - d] : 0;
        __syncthreads();
        a[t] += u;
        __syncthreads();
    }
    boff[t] = a[t] - v;   // exclusive
}

__global__ __launch_bounds__(256) void scan3(const int* __restrict__ loc,
                                             const int* __restrict__ boff,
                                             int* __restrict__ rowoff,
                                             int* __restrict__ cursor) {
    int i = blockIdx.x * 256 + threadIdx.x;
    if (i < NN) {
        int v = loc[i] + boff[i >> 10];
        rowoff[i] = v;
        cursor[i] = v;
    }
    if (i == 0) rowoff[NN] = NE;
}

// ---------------- CSR placement ----------------
__global__ __launch_bounds__(256) void place_kernel(const int* __restrict__ src,
                                                    const int* __restrict__ dst,
                                                    int* __restrict__ cursor,
                                                    int* __restrict__ csr) {
    int e = blockIdx.x * 256 + threadIdx.x;
    if (e < NE) {
        int pos = atomicAdd(&cursor[dst[e]], 1);
        csr[pos] = src[e];
    }
}

// ---------------- fp32 -> bf16 convert ----------------
__global__ __launch_bounds__(256) void tobf16_kernel(const float* __restrict__ in,
                                                     unsigned short* __restrict__ outp) {
    int i = blockIdx.x * 256 + threadIdx.x;   // one per 8 elements
    const float4 a = *(const float4*)&in[(size_t)i * 8];
    const float4 b = *(const float4*)&in[(size_t)i * 8 + 4];
    unsigned short o[8] = {f2bf(a.x), f2bf(a.y), f2bf(a.z), f2bf(a.w),
                           f2bf(b.x), f2bf(b.y), f2bf(b.z), f2bf(b.w)};
    *(bf16x8*)&outp[(size_t)i * 8] = *(bf16x8*)o;
}

// ---------------- gather mean (bf16 in, bf16 out, fp32 accum) ----------------
// 16 lanes per node, 8 bf16 (16B) per lane.
__global__ __launch_bounds__(256) void gather_bf16(const unsigned short* __restrict__ feat,
                                                   const int* __restrict__ rowoff,
                                                   const int* __restrict__ csr,
                                                   const int* __restrict__ cnt,
                                                   unsigned short* __restrict__ mean) {
    const int node = blockIdx.x * 16 + (threadIdx.x >> 4);
    const int l8 = (threadIdx.x & 15) * 8;
    const int beg = rowoff[node], end = rowoff[node + 1];
    float acc[8] = {0, 0, 0, 0, 0, 0, 0, 0};
    int j = beg;
    for (; j + 1 < end; j += 2) {
        int s0 = csr[j], s1 = csr[j + 1];
        bf16x8 v0 = *(const bf16x8*)&feat[(size_t)s0 * DD + l8];
        bf16x8 v1 = *(const bf16x8*)&feat[(size_t)s1 * DD + l8];
        #pragma unroll
        for (int i = 0; i < 8; ++i)
            acc[i] += bf2f((unsigned short)v0[i]) + bf2f((unsigned short)v1[i]);
    }
    if (j < end) {
        int s0 = csr[j];
        bf16x8 v0 = *(const bf16x8*)&feat[(size_t)s0 * DD + l8];
        #pragma unroll
        for (int i = 0; i < 8; ++i) acc[i] += bf2f((unsigned short)v0[i]);
    }
    const float inv = 1.0f / fmaxf((float)cnt[node], 1.0f);
    unsigned short o[8];
    #pragma unroll
    for (int i = 0; i < 8; ++i) o[i] = f2bf(acc[i] * inv);
    *(bf16x8*)&mean[(size_t)node * DD + l8] = *(bf16x8*)o;
}

// ---------------- combine via MFMA: out = mean@Wl^T + self@Wr^T + b --------
// B in LDS, fragment-ordered: Bs[(ko*128 + j)*8 + kk] = W[j][ko*8+kk] (bf16),
// ko 0..15 = Wl octets (k 0..127), ko 16..31 = Wr octets. 64 KB.
// Wave tile: 16 nodes x 128 cols (8 MFMA col-tiles), A-frags straight from global.
__global__ __launch_bounds__(256) void combine_mfma(
    const unsigned short* __restrict__ mean, const unsigned short* __restrict__ self,
    const float* __restrict__ Wl, const float* __restrict__ Wr,
    const float* __restrict__ bias, void* __restrict__ outp,
    int out_bf16, int do_relu)
{
    __shared__ unsigned short Bs[32 * 128 * 8];   // 64 KB
    const int t = threadIdx.x;

    // fill B (coalesced reads: consecutive threads cover one W row's k range)
    for (int idx = t; idx < 2 * 16 * 128; idx += 256) {
        const int ko_l = idx & 15;            // k-octet within half
        const int j    = (idx >> 4) & 127;    // W row = output col
        const int half = idx >> 11;           // 0 = Wl, 1 = Wr
        const float* W = half ? Wr : Wl;
        const float4 w0 = *(const float4*)&W[(size_t)j * DD + ko_l * 8];
        const float4 w1 = *(const float4*)&W[(size_t)j * DD + ko_l * 8 + 4];
        unsigned short o[8] = {f2bf(w0.x), f2bf(w0.y), f2bf(w0.z), f2bf(w0.w),
                               f2bf(w1.x), f2bf(w1.y), f2bf(w1.z), f2bf(w1.w)};
        *(bf16x8*)&Bs[((size_t)(half * 16 + ko_l) * 128 + j) * 8] = *(bf16x8*)o;
    }
    __syncthreads();

    const int wv = t >> 6, lane = t & 63;
    const int m = lane & 15;        // A row within tile / C col
    const int q = lane >> 4;        // quad

    for (int tile = blockIdx.x * 4 + wv; tile < NN / 16; tile += gridDim.x * 4) {
        const size_t arow = ((size_t)tile * 16 + m) * DD;
        f32x4 acc[8];
        #pragma unroll
        for (int jt = 0; jt < 8; ++jt) acc[jt] = (f32x4){0.f, 0.f, 0.f, 0.f};

        #pragma unroll
        for (int kq = 0; kq < 4; ++kq) {                      // mean part, k=0..127
            const bf16x8 a = *(const bf16x8*)&mean[arow + kq * 32 + q * 8];
            #pragma unroll
            for (int jt = 0; jt < 8; ++jt) {
                const bf16x8 b = *(const bf16x8*)&Bs[((size_t)(kq * 4 + q) * 128 + jt * 16 + m) * 8];
                acc[jt] = __builtin_amdgcn_mfma_f32_16x16x32_bf16(a, b, acc[jt], 0, 0, 0);
            }
        }
        #pragma unroll
        for (int kq = 0; kq < 4; ++kq) {                      // self part, k=128..255
            const bf16x8 a = *(const bf16x8*)&self[arow + kq * 32 + q * 8];
            #pragma unroll
            for (int jt = 0; jt < 8; ++jt) {
                const bf16x8 b = *(const bf16x8*)&Bs[((size_t)(16 + kq * 4 + q) * 128 + jt * 16 + m) * 8];
                acc[jt] = __builtin_amdgcn_mfma_f32_16x16x32_bf16(a, b, acc[jt], 0, 0, 0);
            }
        }

        // epilogue: C row = q*4+r, col = jt*16+m
        #pragma unroll
        for (int jt = 0; jt < 8; ++jt) {
            const int col = jt * 16 + m;
            const float bv = bias[col];
            #pragma unroll
            for (int r = 0; r < 4; ++r) {
                const size_t row = (size_t)tile * 16 + q * 4 + r;
                float v = acc[jt][r] + bv;
                if (do_relu) v = fmaxf(v, 0.0f);
                if (out_bf16)
                    ((unsigned short*)outp)[row * DD + col] = f2bf(v);
                else
                    ((float*)outp)[row * DD + col] = v;
            }
        }
    }
}

extern "C" void kernel_launch(void* const* d_in, const int* in_sizes, int n_in,
                              void* d_out, int out_size, void* d_ws, size_t ws_size,
                              hipStream_t stream) {
    const float* x   = (const float*)d_in[0];
    const int*   ei  = (const int*)d_in[1];
    const float* Wl1 = (const float*)d_in[2];
    const float* Wr1 = (const float*)d_in[3];
    const float* b1  = (const float*)d_in[4];
    const float* Wl2 = (const float*)d_in[5];
    const float* Wr2 = (const float*)d_in[6];
    const float* b2  = (const float*)d_in[7];
    const int* src = ei;
    const int* dst = ei + NE;
    float* out = (float*)d_out;

    // workspace layout (bf16 feature tables + CSR scratch)
    unsigned short* xb   = (unsigned short*)d_ws;              // NN*DD
    unsigned short* mean = xb + (size_t)NN * DD;               // NN*DD
    unsigned short* h    = mean + (size_t)NN * DD;             // NN*DD
    int* cnt    = (int*)(h + (size_t)NN * DD);                 // NN
    int* loc    = cnt + NN;                                    // NN
    int* rowoff = loc + NN;                                    // NN+1
    int* cursor = rowoff + NN + 1;                             // NN
    int* bsum   = cursor + NN;                                 // 128
    int* boff   = bsum + 128;                                  // 128
    int* csr    = boff + 128;                                  // NE

    hipMemsetAsync(cnt, 0, NN * sizeof(int), stream);
    count_kernel<<<(NE + 255) / 256, 256, 0, stream>>>(dst, cnt);
    scan1<<<NB, 1024, 0, stream>>>(cnt, loc, bsum);
    scan2<<<1, 128, 0, stream>>>(bsum, boff);
    scan3<<<(NN + 255) / 256, 256, 0, stream>>>(loc, boff, rowoff, cursor);
    place_kernel<<<(NE + 255) / 256, 256, 0, stream>>>(src, dst, cursor, csr);

    tobf16_kernel<<<NN * DD / 8 / 256, 256, 0, stream>>>(x, xb);

    gather_bf16<<<NN / 16, 256, 0, stream>>>(xb, rowoff, csr, cnt, mean);
    combine_mfma<<<512, 256, 0, stream>>>(mean, xb, Wl1, Wr1, b1, h, 1, 1);

    gather_bf16<<<NN / 16, 256, 0, stream>>>(h, rowoff, csr, cnt, mean);
    combine_mfma<<<512, 256, 0, stream>>>(mean, h, Wl2, Wr2, b2, out, 0, 0);
}

// Round 4
// 368.006 us; speedup vs baseline: 15.8139x; 1.3686x over previous
//
#include <hip/hip_runtime.h>
#include <hip/hip_bf16.h>

#define NN 100000
#define NE 1600000
#define DD 128

#define ASHIFT 9            // bucket = dst >> 9 (512-node span)
#define NSPAN  512
#define BK     196          // ceil(100000/512)
#define BCAP   9216         // per-bucket capacity (mean 8192, sd ~90)
#define EPB    4096         // edges per phase-A block
#define NAB    391          // ceil(NE/EPB)

typedef __attribute__((ext_vector_type(8))) short bf16x8;
typedef __attribute__((ext_vector_type(4))) float f32x4;

__device__ inline unsigned short f2bf(float f) {          // RNE float->bf16
    unsigned u = __builtin_bit_cast(unsigned, f);
    u += 0x7fff + ((u >> 16) & 1);
    return (unsigned short)(u >> 16);
}
__device__ inline float bf2f(unsigned short h) {
    return __builtin_bit_cast(float, (unsigned)h << 16);
}

// ---------------- bucket cursor init ----------------
__global__ __launch_bounds__(256) void initcur_kernel(int* __restrict__ gcur) {
    int t = threadIdx.x;
    if (t < BK) gcur[t] = t * BCAP;
}

// ---------------- phase A: bin edges into 196 buckets ----------------
__global__ __launch_bounds__(256) void bucketA(const int* __restrict__ src,
                                               const int* __restrict__ dst,
                                               int* __restrict__ gcur,
                                               int2* __restrict__ pairs) {
    __shared__ int hist[BK];
    __shared__ int gbase[BK];
    __shared__ int lcur[BK];
    const int t  = threadIdx.x;
    const int e0 = blockIdx.x * EPB;

    for (int i = t; i < BK; i += 256) hist[i] = 0;
    __syncthreads();
    for (int i = t; i < EPB; i += 256) {
        int e = e0 + i;
        if (e < NE) atomicAdd(&hist[dst[e] >> ASHIFT], 1);
    }
    __syncthreads();
    for (int i = t; i < BK; i += 256) {
        int c = hist[i];
        gbase[i] = c ? atomicAdd(&gcur[i], c) : 0;   // block-private run
        lcur[i] = 0;
    }
    __syncthreads();
    for (int i = t; i < EPB; i += 256) {
        int e = e0 + i;
        if (e < NE) {
            int d = dst[e];
            int b = d >> ASHIFT;
            int r = atomicAdd(&lcur[b], 1);
            pairs[gbase[b] + r] = (int2){src[e], d};
        }
    }
}

// ---------------- bucket-size exclusive scan (196 values) ----------------
__global__ __launch_bounds__(256) void bucketScan(const int* __restrict__ gcur,
                                                  int* __restrict__ bbase) {
    __shared__ int a[256];
    int t = threadIdx.x;
    int v = (t < BK) ? (gcur[t] - t * BCAP) : 0;
    a[t] = v;
    __syncthreads();
    #pragma unroll
    for (int d = 1; d < 256; d <<= 1) {
        int u = (t >= d) ? a[t - d] : 0;
        __syncthreads();
        a[t] += u;
        __syncthreads();
    }
    if (t < BK) bbase[t] = a[t] - v;
}

// ---------------- phase B: per-bucket CSR finalize (+cnt, +rowoff) --------
__global__ __launch_bounds__(256) void bucketB(const int2* __restrict__ pairs,
                                               const int* __restrict__ gcur,
                                               const int* __restrict__ bbase,
                                               int* __restrict__ cnt,
                                               int* __restrict__ rowoff,
                                               int* __restrict__ csr) {
    __shared__ int hist[NSPAN];
    __shared__ int scanbuf[NSPAN];
    const int b = blockIdx.x, t = threadIdx.x;
    const int n0    = b << ASHIFT;
    const int nodeN = min(NSPAN, NN - n0);
    const int sz    = gcur[b] - b * BCAP;
    const int base  = bbase[b];
    const int2* ep  = &pairs[(size_t)b * BCAP];

    for (int i = t; i < NSPAN; i += 256) hist[i] = 0;
    __syncthreads();
    for (int i = t; i < sz; i += 256) atomicAdd(&hist[ep[i].y - n0], 1);
    __syncthreads();
    for (int i = t; i < nodeN; i += 256) cnt[n0 + i] = hist[i];
    for (int i = t; i < NSPAN; i += 256) scanbuf[i] = hist[i];
    __syncthreads();
    // Hillis-Steele inclusive scan over 512 entries with 256 threads
    #pragma unroll
    for (int d = 1; d < NSPAN; d <<= 1) {
        int v0 = (t >= d) ? scanbuf[t - d] : 0;
        int v1 = (t + 256 >= d) ? scanbuf[t + 256 - d] : 0;
        __syncthreads();
        scanbuf[t] += v0;
        scanbuf[t + 256] += v1;
        __syncthreads();
    }
    for (int i = t; i < NSPAN; i += 256) {
        int excl = scanbuf[i] - hist[i];
        if (i < nodeN) rowoff[n0 + i] = base + excl;
        hist[i] = excl;                     // reuse as cursor
    }
    if (b == BK - 1 && t == 0) rowoff[NN] = NE;
    __syncthreads();
    for (int i = t; i < sz; i += 256) {
        int2 e = ep[i];
        int r = atomicAdd(&hist[e.y - n0], 1);
        csr[base + r] = e.x;                // block-private ~32KB window
    }
}

// ---------------- fp32 -> bf16 convert ----------------
__global__ __launch_bounds__(256) void tobf16_kernel(const float* __restrict__ in,
                                                     unsigned short* __restrict__ outp) {
    int i = blockIdx.x * 256 + threadIdx.x;   // one per 8 elements
    const float4 a = *(const float4*)&in[(size_t)i * 8];
    const float4 b = *(const float4*)&in[(size_t)i * 8 + 4];
    unsigned short o[8] = {f2bf(a.x), f2bf(a.y), f2bf(a.z), f2bf(a.w),
                           f2bf(b.x), f2bf(b.y), f2bf(b.z), f2bf(b.w)};
    *(bf16x8*)&outp[(size_t)i * 8] = *(bf16x8*)o;
}

// ---------------- gather mean (bf16 in, bf16 out, fp32 accum) ----------------
// 16 lanes per node, 8 bf16 (16B) per lane.
__global__ __launch_bounds__(256) void gather_bf16(const unsigned short* __restrict__ feat,
                                                   const int* __restrict__ rowoff,
                                                   const int* __restrict__ csr,
                                                   const int* __restrict__ cnt,
                                                   unsigned short* __restrict__ mean) {
    const int node = blockIdx.x * 16 + (threadIdx.x >> 4);
    const int l8 = (threadIdx.x & 15) * 8;
    const int beg = rowoff[node], end = rowoff[node + 1];
    float acc[8] = {0, 0, 0, 0, 0, 0, 0, 0};
    int j = beg;
    for (; j + 1 < end; j += 2) {
        int s0 = csr[j], s1 = csr[j + 1];
        bf16x8 v0 = *(const bf16x8*)&feat[(size_t)s0 * DD + l8];
        bf16x8 v1 = *(const bf16x8*)&feat[(size_t)s1 * DD + l8];
        #pragma unroll
        for (int i = 0; i < 8; ++i)
            acc[i] += bf2f((unsigned short)v0[i]) + bf2f((unsigned short)v1[i]);
    }
    if (j < end) {
        int s0 = csr[j];
        bf16x8 v0 = *(const bf16x8*)&feat[(size_t)s0 * DD + l8];
        #pragma unroll
        for (int i = 0; i < 8; ++i) acc[i] += bf2f((unsigned short)v0[i]);
    }
    const float inv = 1.0f / fmaxf((float)cnt[node], 1.0f);
    unsigned short o[8];
    #pragma unroll
    for (int i = 0; i < 8; ++i) o[i] = f2bf(acc[i] * inv);
    *(bf16x8*)&mean[(size_t)node * DD + l8] = *(bf16x8*)o;
}

// ---------------- combine via MFMA: out = mean@Wl^T + self@Wr^T + b --------
__global__ __launch_bounds__(256) void combine_mfma(
    const unsigned short* __restrict__ mean, const unsigned short* __restrict__ self,
    const float* __restrict__ Wl, const float* __restrict__ Wr,
    const float* __restrict__ bias, void* __restrict__ outp,
    int out_bf16, int do_relu)
{
    __shared__ unsigned short Bs[32 * 128 * 8];   // 64 KB
    const int t = threadIdx.x;

    for (int idx = t; idx < 2 * 16 * 128; idx += 256) {
        const int ko_l = idx & 15;
        const int j    = (idx >> 4) & 127;
        const int half = idx >> 11;
        const float* W = half ? Wr : Wl;
        const float4 w0 = *(const float4*)&W[(size_t)j * DD + ko_l * 8];
        const float4 w1 = *(const float4*)&W[(size_t)j * DD + ko_l * 8 + 4];
        unsigned short o[8] = {f2bf(w0.x), f2bf(w0.y), f2bf(w0.z), f2bf(w0.w),
                               f2bf(w1.x), f2bf(w1.y), f2bf(w1.z), f2bf(w1.w)};
        *(bf16x8*)&Bs[((size_t)(half * 16 + ko_l) * 128 + j) * 8] = *(bf16x8*)o;
    }
    __syncthreads();

    const int wv = t >> 6, lane = t & 63;
    const int m = lane & 15;
    const int q = lane >> 4;

    for (int tile = blockIdx.x * 4 + wv; tile < NN / 16; tile += gridDim.x * 4) {
        const size_t arow = ((size_t)tile * 16 + m) * DD;
        f32x4 acc[8];
        #pragma unroll
        for (int jt = 0; jt < 8; ++jt) acc[jt] = (f32x4){0.f, 0.f, 0.f, 0.f};

        #pragma unroll
        for (int kq = 0; kq < 4; ++kq) {
            const bf16x8 a = *(const bf16x8*)&mean[arow + kq * 32 + q * 8];
            #pragma unroll
            for (int jt = 0; jt < 8; ++jt) {
                const bf16x8 b = *(const bf16x8*)&Bs[((size_t)(kq * 4 + q) * 128 + jt * 16 + m) * 8];
                acc[jt] = __builtin_amdgcn_mfma_f32_16x16x32_bf16(a, b, acc[jt], 0, 0, 0);
            }
        }
        #pragma unroll
        for (int kq = 0; kq < 4; ++kq) {
            const bf16x8 a = *(const bf16x8*)&self[arow + kq * 32 + q * 8];
            #pragma unroll
            for (int jt = 0; jt < 8; ++jt) {
                const bf16x8 b = *(const bf16x8*)&Bs[((size_t)(16 + kq * 4 + q) * 128 + jt * 16 + m) * 8];
                acc[jt] = __builtin_amdgcn_mfma_f32_16x16x32_bf16(a, b, acc[jt], 0, 0, 0);
            }
        }

        #pragma unroll
        for (int jt = 0; jt < 8; ++jt) {
            const int col = jt * 16 + m;
            const float bv = bias[col];
            #pragma unroll
            for (int r = 0; r < 4; ++r) {
                const size_t row = (size_t)tile * 16 + q * 4 + r;
                float v = acc[jt][r] + bv;
                if (do_relu) v = fmaxf(v, 0.0f);
                if (out_bf16)
                    ((unsigned short*)outp)[row * DD + col] = f2bf(v);
                else
                    ((float*)outp)[row * DD + col] = v;
            }
        }
    }
}

extern "C" void kernel_launch(void* const* d_in, const int* in_sizes, int n_in,
                              void* d_out, int out_size, void* d_ws, size_t ws_size,
                              hipStream_t stream) {
    const float* x   = (const float*)d_in[0];
    const int*   ei  = (const int*)d_in[1];
    const float* Wl1 = (const float*)d_in[2];
    const float* Wr1 = (const float*)d_in[3];
    const float* b1  = (const float*)d_in[4];
    const float* Wl2 = (const float*)d_in[5];
    const float* Wr2 = (const float*)d_in[6];
    const float* b2  = (const float*)d_in[7];
    const int* src = ei;
    const int* dst = ei + NE;
    float* out = (float*)d_out;

    // workspace layout
    unsigned short* xb   = (unsigned short*)d_ws;              // NN*DD  (25.6MB)
    unsigned short* mean = xb + (size_t)NN * DD;               // NN*DD  (25.6MB)
    unsigned short* h    = mean + (size_t)NN * DD;             // NN*DD  (25.6MB)
    int2* pairs = (int2*)(h + (size_t)NN * DD);                // BK*BCAP (14.45MB)
    int*  gcur   = (int*)(pairs + (size_t)BK * BCAP);          // BK
    int*  bbase  = gcur + BK;                                  // BK
    int*  cnt    = bbase + BK;                                 // NN
    int*  rowoff = cnt + NN;                                   // NN+1
    int*  csr    = rowoff + NN + 1;                            // NE (6.4MB)

    initcur_kernel<<<1, 256, 0, stream>>>(gcur);
    bucketA<<<NAB, 256, 0, stream>>>(src, dst, gcur, pairs);
    bucketScan<<<1, 256, 0, stream>>>(gcur, bbase);
    bucketB<<<BK, 256, 0, stream>>>(pairs, gcur, bbase, cnt, rowoff, csr);

    tobf16_kernel<<<NN * DD / 8 / 256, 256, 0, stream>>>(x, xb);

    gather_bf16<<<NN / 16, 256, 0, stream>>>(xb, rowoff, csr, cnt, mean);
    combine_mfma<<<512, 256, 0, stream>>>(mean, xb, Wl1, Wr1, b1, h, 1, 1);

    gather_bf16<<<NN / 16, 256, 0, stream>>>(h, rowoff, csr, cnt, mean);
    combine_mfma<<<512, 256, 0, stream>>>(mean, h, Wl2, Wr2, b2, out, 0, 0);
}

// Round 5
// 362.431 us; speedup vs baseline: 16.0571x; 1.0154x over previous
//
#include <hip/hip_runtime.h>
#include <hip/hip_bf16.h>

#define NN 100000
#define NE 1600000
#define DD 128

#define ASHIFT 9            // bucket = dst >> 9 (512-node span)
#define NSPAN  512
#define BK     196          // ceil(100000/512)
#define BCAP   9216         // per-bucket capacity (mean 8192, sd ~90)
#define EPB    4096         // edges per phase-A block
#define NAB    391          // ceil(NE/EPB)

typedef __attribute__((ext_vector_type(8))) short bf16x8;
typedef __attribute__((ext_vector_type(4))) float f32x4;

__device__ inline unsigned short f2bf(float f) {          // RNE float->bf16
    unsigned u = __builtin_bit_cast(unsigned, f);
    u += 0x7fff + ((u >> 16) & 1);
    return (unsigned short)(u >> 16);
}
__device__ inline float bf2f(unsigned short h) {
    return __builtin_bit_cast(float, (unsigned)h << 16);
}

// ---------------- phase A: bin edges into 196 buckets ----------------
// pairs entry: (local_dst << 17) | src   (src < 2^17, local < 2^9)
__global__ __launch_bounds__(256) void bucketA(const int* __restrict__ src,
                                               const int* __restrict__ dst,
                                               int* __restrict__ gcur,
                                               int* __restrict__ pairs) {
    __shared__ int hist[BK];
    __shared__ int gbase[BK];
    __shared__ int lcur[BK];
    const int t  = threadIdx.x;
    const int e0 = blockIdx.x * EPB;

    for (int i = t; i < BK; i += 256) hist[i] = 0;
    __syncthreads();
    for (int i = t; i < EPB; i += 256) {
        int e = e0 + i;
        if (e < NE) atomicAdd(&hist[dst[e] >> ASHIFT], 1);
    }
    __syncthreads();
    for (int i = t; i < BK; i += 256) {
        int c = hist[i];
        gbase[i] = i * BCAP + (c ? atomicAdd(&gcur[i], c) : 0);  // block-private run
        lcur[i] = 0;
    }
    __syncthreads();
    for (int i = t; i < EPB; i += 256) {
        int e = e0 + i;
        if (e < NE) {
            int d = dst[e];
            int b = d >> ASHIFT;
            int r = atomicAdd(&lcur[b], 1);
            pairs[gbase[b] + r] = ((d & (NSPAN - 1)) << 17) | src[e];
        }
    }
}

// ---------------- phase B: per-bucket CSR finalize (+cnt, +rowoff) --------
// also derives its own global base by scanning the 196 bucket sizes in LDS.
__global__ __launch_bounds__(256) void bucketB(const int* __restrict__ pairs,
                                               const int* __restrict__ gcur,
                                               int* __restrict__ cnt,
                                               int* __restrict__ rowoff,
                                               int* __restrict__ csr) {
    __shared__ int bs[256];
    __shared__ int hist[NSPAN];
    __shared__ int scanbuf[NSPAN];
    const int b = blockIdx.x, t = threadIdx.x;

    // bucket-size scan (196 values) -> this bucket's global base
    int v = (t < BK) ? gcur[t] : 0;
    bs[t] = v;
    __syncthreads();
    #pragma unroll
    for (int d = 1; d < 256; d <<= 1) {
        int u = (t >= d) ? bs[t - d] : 0;
        __syncthreads();
        bs[t] += u;
        __syncthreads();
    }
    const int sz   = gcur[b];
    const int base = bs[b] - sz;          // exclusive prefix

    const int n0    = b << ASHIFT;
    const int nodeN = min(NSPAN, NN - n0);
    const int* ep   = &pairs[(size_t)b * BCAP];

    for (int i = t; i < NSPAN; i += 256) hist[i] = 0;
    __syncthreads();
    for (int i = t; i < sz; i += 256) atomicAdd(&hist[((unsigned)ep[i]) >> 17], 1);
    __syncthreads();
    for (int i = t; i < nodeN; i += 256) cnt[n0 + i] = hist[i];
    for (int i = t; i < NSPAN; i += 256) scanbuf[i] = hist[i];
    __syncthreads();
    // Hillis-Steele inclusive scan over 512 entries with 256 threads
    #pragma unroll
    for (int d = 1; d < NSPAN; d <<= 1) {
        int v0 = (t >= d) ? scanbuf[t - d] : 0;
        int v1 = (t + 256 >= d) ? scanbuf[t + 256 - d] : 0;
        __syncthreads();
        scanbuf[t] += v0;
        scanbuf[t + 256] += v1;
        __syncthreads();
    }
    for (int i = t; i < NSPAN; i += 256) {
        int excl = scanbuf[i] - hist[i];
        if (i < nodeN) rowoff[n0 + i] = base + excl;
        hist[i] = excl;                     // reuse as cursor
    }
    if (b == BK - 1 && t == 0) rowoff[NN] = NE;
    __syncthreads();
    for (int i = t; i < sz; i += 256) {
        int p = ep[i];
        int r = atomicAdd(&hist[((unsigned)p) >> 17], 1);
        csr[base + r] = p & 0x1FFFF;        // block-private ~32KB window
    }
}

// ---------------- fp32 -> bf16 convert ----------------
__global__ __launch_bounds__(256) void tobf16_kernel(const float* __restrict__ in,
                                                     unsigned short* __restrict__ outp) {
    int i = blockIdx.x * 256 + threadIdx.x;   // one per 8 elements
    const float4 a = *(const float4*)&in[(size_t)i * 8];
    const float4 b = *(const float4*)&in[(size_t)i * 8 + 4];
    unsigned short o[8] = {f2bf(a.x), f2bf(a.y), f2bf(a.z), f2bf(a.w),
                           f2bf(b.x), f2bf(b.y), f2bf(b.z), f2bf(b.w)};
    *(bf16x8*)&outp[(size_t)i * 8] = *(bf16x8*)o;
}

// ---------------- gather mean (bf16 in, bf16 out, fp32 accum) ----------------
// 16 lanes per node, 8 bf16 (16B) per lane; 4-edge unroll, 2 acc chains.
__global__ __launch_bounds__(256) void gather_bf16(const unsigned short* __restrict__ feat,
                                                   const int* __restrict__ rowoff,
                                                   const int* __restrict__ csr,
                                                   const int* __restrict__ cnt,
                                                   unsigned short* __restrict__ mean) {
    const int node = blockIdx.x * 16 + (threadIdx.x >> 4);
    const int l8 = (threadIdx.x & 15) * 8;
    const int beg = rowoff[node], end = rowoff[node + 1];
    float a0[8] = {0, 0, 0, 0, 0, 0, 0, 0};
    float a1[8] = {0, 0, 0, 0, 0, 0, 0, 0};
    int j = beg;
    for (; j + 3 < end; j += 4) {
        int s0 = csr[j], s1 = csr[j + 1], s2 = csr[j + 2], s3 = csr[j + 3];
        bf16x8 v0 = *(const bf16x8*)&feat[(size_t)s0 * DD + l8];
        bf16x8 v1 = *(const bf16x8*)&feat[(size_t)s1 * DD + l8];
        bf16x8 v2 = *(const bf16x8*)&feat[(size_t)s2 * DD + l8];
        bf16x8 v3 = *(const bf16x8*)&feat[(size_t)s3 * DD + l8];
        #pragma unroll
        for (int i = 0; i < 8; ++i) {
            a0[i] += bf2f((unsigned short)v0[i]) + bf2f((unsigned short)v2[i]);
            a1[i] += bf2f((unsigned short)v1[i]) + bf2f((unsigned short)v3[i]);
        }
    }
    for (; j < end; ++j) {
        int s0 = csr[j];
        bf16x8 v0 = *(const bf16x8*)&feat[(size_t)s0 * DD + l8];
        #pragma unroll
        for (int i = 0; i < 8; ++i) a0[i] += bf2f((unsigned short)v0[i]);
    }
    const float inv = 1.0f / fmaxf((float)cnt[node], 1.0f);
    unsigned short o[8];
    #pragma unroll
    for (int i = 0; i < 8; ++i) o[i] = f2bf((a0[i] + a1[i]) * inv);
    *(bf16x8*)&mean[(size_t)node * DD + l8] = *(bf16x8*)o;
}

// ---------------- combine via MFMA: out = mean@Wl^T + self@Wr^T + b --------
__global__ __launch_bounds__(256) void combine_mfma(
    const unsigned short* __restrict__ mean, const unsigned short* __restrict__ self,
    const float* __restrict__ Wl, const float* __restrict__ Wr,
    const float* __restrict__ bias, void* __restrict__ outp,
    int out_bf16, int do_relu)
{
    __shared__ unsigned short Bs[32 * 128 * 8];   // 64 KB
    const int t = threadIdx.x;

    for (int idx = t; idx < 2 * 16 * 128; idx += 256) {
        const int ko_l = idx & 15;
        const int j    = (idx >> 4) & 127;
        const int half = idx >> 11;
        const float* W = half ? Wr : Wl;
        const float4 w0 = *(const float4*)&W[(size_t)j * DD + ko_l * 8];
        const float4 w1 = *(const float4*)&W[(size_t)j * DD + ko_l * 8 + 4];
        unsigned short o[8] = {f2bf(w0.x), f2bf(w0.y), f2bf(w0.z), f2bf(w0.w),
                               f2bf(w1.x), f2bf(w1.y), f2bf(w1.z), f2bf(w1.w)};
        *(bf16x8*)&Bs[((size_t)(half * 16 + ko_l) * 128 + j) * 8] = *(bf16x8*)o;
    }
    __syncthreads();

    const int wv = t >> 6, lane = t & 63;
    const int m = lane & 15;
    const int q = lane >> 4;

    for (int tile = blockIdx.x * 4 + wv; tile < NN / 16; tile += gridDim.x * 4) {
        const size_t arow = ((size_t)tile * 16 + m) * DD;
        f32x4 acc[8];
        #pragma unroll
        for (int jt = 0; jt < 8; ++jt) acc[jt] = (f32x4){0.f, 0.f, 0.f, 0.f};

        #pragma unroll
        for (int kq = 0; kq < 4; ++kq) {
            const bf16x8 a = *(const bf16x8*)&mean[arow + kq * 32 + q * 8];
            #pragma unroll
            for (int jt = 0; jt < 8; ++jt) {
                const bf16x8 b = *(const bf16x8*)&Bs[((size_t)(kq * 4 + q) * 128 + jt * 16 + m) * 8];
                acc[jt] = __builtin_amdgcn_mfma_f32_16x16x32_bf16(a, b, acc[jt], 0, 0, 0);
            }
        }
        #pragma unroll
        for (int kq = 0; kq < 4; ++kq) {
            const bf16x8 a = *(const bf16x8*)&self[arow + kq * 32 + q * 8];
            #pragma unroll
            for (int jt = 0; jt < 8; ++jt) {
                const bf16x8 b = *(const bf16x8*)&Bs[((size_t)(16 + kq * 4 + q) * 128 + jt * 16 + m) * 8];
                acc[jt] = __builtin_amdgcn_mfma_f32_16x16x32_bf16(a, b, acc[jt], 0, 0, 0);
            }
        }

        #pragma unroll
        for (int jt = 0; jt < 8; ++jt) {
            const int col = jt * 16 + m;
            const float bv = bias[col];
            #pragma unroll
            for (int r = 0; r < 4; ++r) {
                const size_t row = (size_t)tile * 16 + q * 4 + r;
                float v = acc[jt][r] + bv;
                if (do_relu) v = fmaxf(v, 0.0f);
                if (out_bf16)
                    ((unsigned short*)outp)[row * DD + col] = f2bf(v);
                else
                    ((float*)outp)[row * DD + col] = v;
            }
        }
    }
}

extern "C" void kernel_launch(void* const* d_in, const int* in_sizes, int n_in,
                              void* d_out, int out_size, void* d_ws, size_t ws_size,
                              hipStream_t stream) {
    const float* x   = (const float*)d_in[0];
    const int*   ei  = (const int*)d_in[1];
    const float* Wl1 = (const float*)d_in[2];
    const float* Wr1 = (const float*)d_in[3];
    const float* b1  = (const float*)d_in[4];
    const float* Wl2 = (const float*)d_in[5];
    const float* Wr2 = (const float*)d_in[6];
    const float* b2  = (const float*)d_in[7];
    const int* src = ei;
    const int* dst = ei + NE;
    float* out = (float*)d_out;

    // workspace layout
    unsigned short* xb   = (unsigned short*)d_ws;              // NN*DD  (25.6MB)
    unsigned short* mean = xb + (size_t)NN * DD;               // NN*DD  (25.6MB)
    unsigned short* h    = mean + (size_t)NN * DD;             // NN*DD  (25.6MB)
    int*  pairs  = (int*)(h + (size_t)NN * DD);                // BK*BCAP (7.2MB)
    int*  gcur   = pairs + (size_t)BK * BCAP;                  // BK
    int*  cnt    = gcur + BK;                                  // NN
    int*  rowoff = cnt + NN;                                   // NN+1
    int*  csr    = rowoff + NN + 1;                            // NE (6.4MB)

    hipMemsetAsync(gcur, 0, BK * sizeof(int), stream);
    bucketA<<<NAB, 256, 0, stream>>>(src, dst, gcur, pairs);
    bucketB<<<BK, 256, 0, stream>>>(pairs, gcur, cnt, rowoff, csr);

    tobf16_kernel<<<NN * DD / 8 / 256, 256, 0, stream>>>(x, xb);

    gather_bf16<<<NN / 16, 256, 0, stream>>>(xb, rowoff, csr, cnt, mean);
    combine_mfma<<<512, 256, 0, stream>>>(mean, xb, Wl1, Wr1, b1, h, 1, 1);

    gather_bf16<<<NN / 16, 256, 0, stream>>>(h, rowoff, csr, cnt, mean);
    combine_mfma<<<512, 256, 0, stream>>>(mean, h, Wl2, Wr2, b2, out, 0, 0);
}

// Round 6
// 330.520 us; speedup vs baseline: 17.6074x; 1.0965x over previous
//
#include <hip/hip_runtime.h>
#include <hip/hip_bf16.h>

#define NN 100000
#define NE 1600000
#define DD 128

#define ASHIFT 9            // bucket = dst >> 9 (512-node span)
#define NSPAN  512
#define BK     196          // ceil(100000/512)
#define BCAP   9216         // per-bucket capacity (mean 8192, sd ~90)
#define EPB    4096         // edges per phase-A block
#define NAB    391          // ceil(NE/EPB)

typedef __attribute__((ext_vector_type(8))) short bf16x8;
typedef __attribute__((ext_vector_type(4))) float f32x4;
typedef __attribute__((ext_vector_type(2))) float f32x2;

__device__ inline unsigned short f2bf(float f) {          // RNE float->bf16
    unsigned u = __builtin_bit_cast(unsigned, f);
    u += 0x7fff + ((u >> 16) & 1);
    return (unsigned short)(u >> 16);
}
__device__ inline float bf2f(unsigned short h) {
    return __builtin_bit_cast(float, (unsigned)h << 16);
}

// ---------------- phase A: bin edges into 196 buckets ----------------
// pairs entry: (local_dst << 17) | src   (src < 2^17, local < 2^9)
__global__ __launch_bounds__(256) void bucketA(const int* __restrict__ src,
                                               const int* __restrict__ dst,
                                               int* __restrict__ gcur,
                                               int* __restrict__ pairs) {
    __shared__ int hist[BK];
    __shared__ int gbase[BK];
    __shared__ int lcur[BK];
    const int t  = threadIdx.x;
    const int e0 = blockIdx.x * EPB;

    for (int i = t; i < BK; i += 256) hist[i] = 0;
    __syncthreads();
    for (int i = t; i < EPB; i += 256) {
        int e = e0 + i;
        if (e < NE) atomicAdd(&hist[dst[e] >> ASHIFT], 1);
    }
    __syncthreads();
    for (int i = t; i < BK; i += 256) {
        int c = hist[i];
        gbase[i] = i * BCAP + (c ? atomicAdd(&gcur[i], c) : 0);  // block-private run
        lcur[i] = 0;
    }
    __syncthreads();
    for (int i = t; i < EPB; i += 256) {
        int e = e0 + i;
        if (e < NE) {
            int d = dst[e];
            int b = d >> ASHIFT;
            int r = atomicAdd(&lcur[b], 1);
            pairs[gbase[b] + r] = ((d & (NSPAN - 1)) << 17) | src[e];
        }
    }
}

// ---------------- phase B: per-bucket CSR finalize (+cnt, +rowoff) --------
__global__ __launch_bounds__(256) void bucketB(const int* __restrict__ pairs,
                                               const int* __restrict__ gcur,
                                               int* __restrict__ cnt,
                                               int* __restrict__ rowoff,
                                               int* __restrict__ csr) {
    __shared__ int bs[256];
    __shared__ int hist[NSPAN];
    __shared__ int scanbuf[NSPAN];
    const int b = blockIdx.x, t = threadIdx.x;

    int v = (t < BK) ? gcur[t] : 0;
    bs[t] = v;
    __syncthreads();
    #pragma unroll
    for (int d = 1; d < 256; d <<= 1) {
        int u = (t >= d) ? bs[t - d] : 0;
        __syncthreads();
        bs[t] += u;
        __syncthreads();
    }
    const int sz   = gcur[b];
    const int base = bs[b] - sz;          // exclusive prefix

    const int n0    = b << ASHIFT;
    const int nodeN = min(NSPAN, NN - n0);
    const int* ep   = &pairs[(size_t)b * BCAP];

    for (int i = t; i < NSPAN; i += 256) hist[i] = 0;
    __syncthreads();
    for (int i = t; i < sz; i += 256) atomicAdd(&hist[((unsigned)ep[i]) >> 17], 1);
    __syncthreads();
    for (int i = t; i < nodeN; i += 256) cnt[n0 + i] = hist[i];
    for (int i = t; i < NSPAN; i += 256) scanbuf[i] = hist[i];
    __syncthreads();
    #pragma unroll
    for (int d = 1; d < NSPAN; d <<= 1) {
        int v0 = (t >= d) ? scanbuf[t - d] : 0;
        int v1 = (t + 256 >= d) ? scanbuf[t + 256 - d] : 0;
        __syncthreads();
        scanbuf[t] += v0;
        scanbuf[t + 256] += v1;
        __syncthreads();
    }
    for (int i = t; i < NSPAN; i += 256) {
        int excl = scanbuf[i] - hist[i];
        if (i < nodeN) rowoff[n0 + i] = base + excl;
        hist[i] = excl;                     // reuse as cursor
    }
    if (b == BK - 1 && t == 0) rowoff[NN] = NE;
    __syncthreads();
    for (int i = t; i < sz; i += 256) {
        int p = ep[i];
        int r = atomicAdd(&hist[((unsigned)p) >> 17], 1);
        csr[base + r] = p & 0x1FFFF;        // block-private ~32KB window
    }
}

// ---------------- fp32 -> bf16 + fp8 convert ----------------
__global__ __launch_bounds__(256) void tofeat_kernel(const float* __restrict__ in,
                                                     unsigned short* __restrict__ outb,
                                                     unsigned char* __restrict__ out8) {
    int i = blockIdx.x * 256 + threadIdx.x;   // one per 8 elements
    const float4 a = *(const float4*)&in[(size_t)i * 8];
    const float4 b = *(const float4*)&in[(size_t)i * 8 + 4];
    unsigned short o[8] = {f2bf(a.x), f2bf(a.y), f2bf(a.z), f2bf(a.w),
                           f2bf(b.x), f2bf(b.y), f2bf(b.z), f2bf(b.w)};
    *(bf16x8*)&outb[(size_t)i * 8] = *(bf16x8*)o;
    unsigned e0 = 0, e1 = 0;
    e0 = __builtin_amdgcn_cvt_pk_fp8_f32(a.x, a.y, e0, false);
    e0 = __builtin_amdgcn_cvt_pk_fp8_f32(a.z, a.w, e0, true);
    e1 = __builtin_amdgcn_cvt_pk_fp8_f32(b.x, b.y, e1, false);
    e1 = __builtin_amdgcn_cvt_pk_fp8_f32(b.z, b.w, e1, true);
    uint2 p = {e0, e1};
    *(uint2*)&out8[(size_t)i * 8] = p;
}

// ---------------- gather mean (fp8 in, bf16 out, fp32 accum) ----------------
// 16 lanes per node, 8 fp8 (8B) per lane; 4-edge unroll, 2 acc chains.
__device__ inline void accum8(float* a, uint2 u) {
    f32x2 p;
    p = __builtin_amdgcn_cvt_pk_f32_fp8(u.x, false); a[0] += p.x; a[1] += p.y;
    p = __builtin_amdgcn_cvt_pk_f32_fp8(u.x, true);  a[2] += p.x; a[3] += p.y;
    p = __builtin_amdgcn_cvt_pk_f32_fp8(u.y, false); a[4] += p.x; a[5] += p.y;
    p = __builtin_amdgcn_cvt_pk_f32_fp8(u.y, true);  a[6] += p.x; a[7] += p.y;
}

__global__ __launch_bounds__(256) void gather_fp8(const unsigned char* __restrict__ feat,
                                                  const int* __restrict__ rowoff,
                                                  const int* __restrict__ csr,
                                                  const int* __restrict__ cnt,
                                                  unsigned short* __restrict__ mean) {
    const int node = blockIdx.x * 16 + (threadIdx.x >> 4);
    const int l8 = (threadIdx.x & 15) * 8;
    const int beg = rowoff[node], end = rowoff[node + 1];
    float a0[8] = {0, 0, 0, 0, 0, 0, 0, 0};
    float a1[8] = {0, 0, 0, 0, 0, 0, 0, 0};
    int j = beg;
    for (; j + 3 < end; j += 4) {
        int s0 = csr[j], s1 = csr[j + 1], s2 = csr[j + 2], s3 = csr[j + 3];
        uint2 u0 = *(const uint2*)&feat[(size_t)s0 * DD + l8];
        uint2 u1 = *(const uint2*)&feat[(size_t)s1 * DD + l8];
        uint2 u2 = *(const uint2*)&feat[(size_t)s2 * DD + l8];
        uint2 u3 = *(const uint2*)&feat[(size_t)s3 * DD + l8];
        accum8(a0, u0); accum8(a1, u1); accum8(a0, u2); accum8(a1, u3);
    }
    for (; j < end; ++j) {
        int s0 = csr[j];
        uint2 u0 = *(const uint2*)&feat[(size_t)s0 * DD + l8];
        accum8(a0, u0);
    }
    const float inv = 1.0f / fmaxf((float)cnt[node], 1.0f);
    unsigned short o[8];
    #pragma unroll
    for (int i = 0; i < 8; ++i) o[i] = f2bf((a0[i] + a1[i]) * inv);
    *(bf16x8*)&mean[(size_t)node * DD + l8] = *(bf16x8*)o;
}

// ---------------- combine via MFMA: out = mean@Wl^T + self@Wr^T + b --------
__global__ __launch_bounds__(256) void combine_mfma(
    const unsigned short* __restrict__ mean, const unsigned short* __restrict__ self,
    const float* __restrict__ Wl, const float* __restrict__ Wr,
    const float* __restrict__ bias, void* __restrict__ outp,
    unsigned char* __restrict__ out8,      // optional fp8 copy (layer-1 h)
    int out_bf16, int do_relu)
{
    __shared__ unsigned short Bs[32 * 128 * 8];   // 64 KB
    const int t = threadIdx.x;

    for (int idx = t; idx < 2 * 16 * 128; idx += 256) {
        const int ko_l = idx & 15;
        const int j    = (idx >> 4) & 127;
        const int half = idx >> 11;
        const float* W = half ? Wr : Wl;
        const float4 w0 = *(const float4*)&W[(size_t)j * DD + ko_l * 8];
        const float4 w1 = *(const float4*)&W[(size_t)j * DD + ko_l * 8 + 4];
        unsigned short o[8] = {f2bf(w0.x), f2bf(w0.y), f2bf(w0.z), f2bf(w0.w),
                               f2bf(w1.x), f2bf(w1.y), f2bf(w1.z), f2bf(w1.w)};
        *(bf16x8*)&Bs[((size_t)(half * 16 + ko_l) * 128 + j) * 8] = *(bf16x8*)o;
    }
    __syncthreads();

    const int wv = t >> 6, lane = t & 63;
    const int m = lane & 15;
    const int q = lane >> 4;

    for (int tile = blockIdx.x * 4 + wv; tile < NN / 16; tile += gridDim.x * 4) {
        const size_t arow = ((size_t)tile * 16 + m) * DD;
        f32x4 acc[8];
        #pragma unroll
        for (int jt = 0; jt < 8; ++jt) acc[jt] = (f32x4){0.f, 0.f, 0.f, 0.f};

        #pragma unroll
        for (int kq = 0; kq < 4; ++kq) {
            const bf16x8 a = *(const bf16x8*)&mean[arow + kq * 32 + q * 8];
            #pragma unroll
            for (int jt = 0; jt < 8; ++jt) {
                const bf16x8 b = *(const bf16x8*)&Bs[((size_t)(kq * 4 + q) * 128 + jt * 16 + m) * 8];
                acc[jt] = __builtin_amdgcn_mfma_f32_16x16x32_bf16(a, b, acc[jt], 0, 0, 0);
            }
        }
        #pragma unroll
        for (int kq = 0; kq < 4; ++kq) {
            const bf16x8 a = *(const bf16x8*)&self[arow + kq * 32 + q * 8];
            #pragma unroll
            for (int jt = 0; jt < 8; ++jt) {
                const bf16x8 b = *(const bf16x8*)&Bs[((size_t)(16 + kq * 4 + q) * 128 + jt * 16 + m) * 8];
                acc[jt] = __builtin_amdgcn_mfma_f32_16x16x32_bf16(a, b, acc[jt], 0, 0, 0);
            }
        }

        #pragma unroll
        for (int jt = 0; jt < 8; ++jt) {
            const int col = jt * 16 + m;
            const float bv = bias[col];
            #pragma unroll
            for (int r = 0; r < 4; ++r) {
                const size_t row = (size_t)tile * 16 + q * 4 + r;
                float v = acc[jt][r] + bv;
                if (do_relu) v = fmaxf(v, 0.0f);
                if (out_bf16)
                    ((unsigned short*)outp)[row * DD + col] = f2bf(v);
                else
                    ((float*)outp)[row * DD + col] = v;
                if (out8) {
                    unsigned p = __builtin_amdgcn_cvt_pk_fp8_f32(v, v, 0u, false);
                    out8[row * DD + col] = (unsigned char)p;
                }
            }
        }
    }
}

extern "C" void kernel_launch(void* const* d_in, const int* in_sizes, int n_in,
                              void* d_out, int out_size, void* d_ws, size_t ws_size,
                              hipStream_t stream) {
    const float* x   = (const float*)d_in[0];
    const int*   ei  = (const int*)d_in[1];
    const float* Wl1 = (const float*)d_in[2];
    const float* Wr1 = (const float*)d_in[3];
    const float* b1  = (const float*)d_in[4];
    const float* Wl2 = (const float*)d_in[5];
    const float* Wr2 = (const float*)d_in[6];
    const float* b2  = (const float*)d_in[7];
    const int* src = ei;
    const int* dst = ei + NE;
    float* out = (float*)d_out;

    // workspace layout
    unsigned short* xb   = (unsigned short*)d_ws;              // NN*DD bf16 (25.6MB)
    unsigned short* mean = xb + (size_t)NN * DD;               // NN*DD bf16 (25.6MB)
    unsigned short* h    = mean + (size_t)NN * DD;             // NN*DD bf16 (25.6MB)
    unsigned char*  x8   = (unsigned char*)(h + (size_t)NN * DD); // NN*DD fp8 (12.8MB)
    unsigned char*  h8   = x8 + (size_t)NN * DD;               // NN*DD fp8 (12.8MB)
    int*  pairs  = (int*)(h8 + (size_t)NN * DD);               // BK*BCAP (7.2MB)
    int*  gcur   = pairs + (size_t)BK * BCAP;                  // BK
    int*  cnt    = gcur + BK;                                  // NN
    int*  rowoff = cnt + NN;                                   // NN+1
    int*  csr    = rowoff + NN + 1;                            // NE (6.4MB)

    hipMemsetAsync(gcur, 0, BK * sizeof(int), stream);
    bucketA<<<NAB, 256, 0, stream>>>(src, dst, gcur, pairs);
    bucketB<<<BK, 256, 0, stream>>>(pairs, gcur, cnt, rowoff, csr);

    tofeat_kernel<<<NN * DD / 8 / 256, 256, 0, stream>>>(x, xb, x8);

    gather_fp8<<<NN / 16, 256, 0, stream>>>(x8, rowoff, csr, cnt, mean);
    combine_mfma<<<512, 256, 0, stream>>>(mean, xb, Wl1, Wr1, b1, h, h8, 1, 1);

    gather_fp8<<<NN / 16, 256, 0, stream>>>(h8, rowoff, csr, cnt, mean);
    combine_mfma<<<512, 256, 0, stream>>>(mean, h, Wl2, Wr2, b2, out, nullptr, 0, 0);
}